// Round 4
// baseline (950.087 us; speedup 1.0000x reference)
//
#include <hip/hip_runtime.h>
#include <hip/hip_cooperative_groups.h>
#include <math.h>

namespace cg = cooperative_groups;

constexpr int MM = 10000;   // N_NODES
constexpr int DD = 256;     // D_IN == D_OUT
constexpr int EE = 320000;  // N_EDGES

constexpr int GRID  = 512;
constexpr int BLK   = 256;
constexpr int NWAVE = GRID * (BLK / 64);  // 2048 waves

// workspace layout (4-byte units)
constexpr size_t O_H   = 0;                     // float MM*DD
constexpr size_t O_SS  = O_H + (size_t)MM * DD; // float MM
constexpr size_t O_SD  = O_SS + MM;             // float MM
constexpr size_t O_SC  = O_SD + MM;             // float EE
constexpr size_t O_DEG = O_SC + EE;             // int MM   (memset 0 pre-launch)
constexpr size_t O_FC  = O_DEG + MM;            // int 1    (fill chunk counter)
constexpr size_t O_RO  = O_FC + 1;              // int MM+1
constexpr size_t O_CUR = O_RO + MM + 1;         // int MM
constexpr size_t O_CSR = O_CUR + MM;            // int EE

constexpr size_t ZT  = (size_t)MM * MM / 4;     // att float4 count = 25e6
constexpr int    CH4 = 4096;                    // float4 per wave-chunk (64 KB)
constexpr int NCHUNK = (int)((ZT + CH4 - 1) / CH4);  // 6104

__global__ __launch_bounds__(BLK, 2)
void gat_fused(const float* __restrict__ X, const float* __restrict__ Wm,
               const float* __restrict__ Asrc, const float* __restrict__ Adst,
               const int* __restrict__ eidx, float* __restrict__ out,
               float* __restrict__ ws) {
    cg::grid_group grid = cg::this_grid();
    const int tid  = threadIdx.x;
    const int wv   = tid >> 6, lane = tid & 63;
    const int gw   = blockIdx.x * 4 + wv;   // global wave id

    float* h       = ws + O_H;
    float* s_ss    = ws + O_SS;
    float* s_sd    = ws + O_SD;
    float* score   = ws + O_SC;
    int*   deg     = (int*)(ws + O_DEG);
    int*   fctr    = (int*)(ws + O_FC);
    int*   row_off = (int*)(ws + O_RO);
    int*   cursor  = (int*)(ws + O_CUR);
    int*   csr     = (int*)(ws + O_CSR);
    const int* src = eidx;
    const int* dst = eidx + EE;
    float*  att    = out + (size_t)MM * DD;
    float4* att4   = (float4*)att;
    const float4* h4 = (const float4*)h;
    float4* out4     = (float4*)out;

    __shared__ float xs[16][68];
    __shared__ float wt[16][68];
    __shared__ int   swsum[4];

    // ---------------- S1: GEMM h = X @ W^T + zero-fill att ----------------
    {
        const int lr = tid >> 2;           // 0..63
        const int lc = (tid & 3) << 2;     // 0,4,8,12
        const int tx = tid & 15, ty = tid >> 4;
        for (int tile = blockIdx.x; tile < 628; tile += GRID) {
            const int bm = (tile % 157) << 6;
            const int bn = (tile / 157) << 6;
            float acc[4][4] = {};
            for (int k0 = 0; k0 < DD; k0 += 16) {
                const int gr = bm + lr;
                float4 xv = make_float4(0.f, 0.f, 0.f, 0.f);
                if (gr < MM) xv = *(const float4*)(X + (size_t)gr * DD + k0 + lc);
                float4 wv4 = *(const float4*)(Wm + (size_t)(bn + lr) * DD + k0 + lc);
                xs[lc + 0][lr] = xv.x;  xs[lc + 1][lr] = xv.y;
                xs[lc + 2][lr] = xv.z;  xs[lc + 3][lr] = xv.w;
                wt[lc + 0][lr] = wv4.x; wt[lc + 1][lr] = wv4.y;
                wt[lc + 2][lr] = wv4.z; wt[lc + 3][lr] = wv4.w;
                __syncthreads();
#pragma unroll
                for (int k = 0; k < 16; ++k) {
                    float4 xr4 = *(const float4*)(&xs[k][ty << 2]);
                    float4 wr4 = *(const float4*)(&wt[k][tx << 2]);
                    float xr[4] = {xr4.x, xr4.y, xr4.z, xr4.w};
                    float wr[4] = {wr4.x, wr4.y, wr4.z, wr4.w};
#pragma unroll
                    for (int i = 0; i < 4; ++i)
#pragma unroll
                        for (int j = 0; j < 4; ++j) acc[i][j] += xr[i] * wr[j];
                }
                __syncthreads();
            }
#pragma unroll
            for (int i = 0; i < 4; ++i) {
                const int r = bm + (ty << 2) + i;
                if (r < MM) {
                    *(float4*)(h + (size_t)r * DD + bn + (tx << 2)) =
                        make_float4(acc[i][0], acc[i][1], acc[i][2], acc[i][3]);
                }
            }
        }
        // self-balancing zero-fill of the 400 MB attention matrix
        while (true) {
            int c = 0;
            if (lane == 0) c = atomicAdd(fctr, 1);
            c = __shfl(c, 0);
            if (c >= NCHUNK) break;
            size_t base = (size_t)c * CH4 + lane;
#pragma unroll
            for (int k = 0; k < CH4 / 64; ++k) {   // 64 iterations, 4 KB/wave each
                size_t p = base + (size_t)k * 64;
                if (p < ZT) att4[p] = make_float4(0.f, 0.f, 0.f, 0.f);
            }
        }
    }
    grid.sync();

    // ---------------- S2: per-node dots ----------------
    for (int node = gw; node < MM; node += NWAVE) {
        float4 a = ((const float4*)Asrc)[lane];
        float4 b = ((const float4*)Adst)[lane];
        float4 v = h4[(size_t)node * 64 + lane];
        float dsv = v.x * a.x + v.y * a.y + v.z * a.z + v.w * a.w;
        float ddv = v.x * b.x + v.y * b.y + v.z * b.z + v.w * b.w;
#pragma unroll
        for (int off = 32; off; off >>= 1) {
            dsv += __shfl_xor(dsv, off);
            ddv += __shfl_xor(ddv, off);
        }
        if (lane == 0) { s_ss[node] = dsv; s_sd[node] = ddv; }
    }
    grid.sync();

    // ---------------- S3: edge scores + degree count ----------------
    for (int e = blockIdx.x * BLK + tid; e < EE; e += GRID * BLK) {
        const int s = src[e], d = dst[e];
        float sc = s_ss[s] + s_sd[d];
        sc = (sc >= 0.f) ? sc : 0.2f * sc;
        score[e] = sc;
        atomicAdd(&deg[d], 1);
    }
    grid.sync();

    // ---------------- S4: exclusive scan (block 0 only) ----------------
    if (blockIdx.x == 0) {
        constexpr int C = 40;   // 256*40 >= MM
        const int i0 = tid * C;
        int total = 0;
#pragma unroll 8
        for (int k = 0; k < C; ++k) { int i = i0 + k; total += (i < MM) ? deg[i] : 0; }
        int incl = total;
#pragma unroll
        for (int off = 1; off < 64; off <<= 1) {
            int u = __shfl_up(incl, off);
            if (lane >= off) incl += u;
        }
        if (lane == 63) swsum[wv] = incl;
        __syncthreads();
        if (tid == 0) {
            int run = 0;
#pragma unroll
            for (int w2 = 0; w2 < 4; ++w2) { int v = swsum[w2]; swsum[w2] = run; run += v; }
        }
        __syncthreads();
        int run = swsum[wv] + incl - total;   // global exclusive prefix
#pragma unroll 8
        for (int k = 0; k < C; ++k) {
            const int i = i0 + k;
            if (i < MM) {
                const int v = deg[i];
                cursor[i] = run;
                run += v;
                row_off[i + 1] = run;
            }
        }
        if (tid == 0) row_off[0] = 0;
    }
    grid.sync();

    // ---------------- S5: CSR scatter ----------------
    for (int e = blockIdx.x * BLK + tid; e < EE; e += GRID * BLK) {
        const int pos = atomicAdd(&cursor[dst[e]], 1);
        csr[pos] = e;
    }
    grid.sync();

    // ---------------- S6: softmax + att scatter + aggregation ----------------
    for (int node = gw; node < MM; node += NWAVE) {
        const int r0 = row_off[node], r1 = row_off[node + 1];
        if (r0 == r1) {  // no incoming edges: keep own transformed features
            out4[(size_t)node * 64 + lane] = h4[(size_t)node * 64 + lane];
            continue;
        }
        // phase 1: max (cache first 4 chunks in registers)
        int e_reg[4];
        float s_reg[4];
        float m = -INFINITY;
#pragma unroll
        for (int c = 0; c < 4; ++c) {
            const int i = r0 + c * 64 + lane;
            const bool vld = i < r1;
            const int e = vld ? csr[i] : 0;
            const float s = vld ? score[e] : -INFINITY;
            e_reg[c] = e; s_reg[c] = s;
            m = fmaxf(m, s);
        }
        for (int i = r0 + 256 + lane; i < r1; i += 64) m = fmaxf(m, score[csr[i]]);
#pragma unroll
        for (int off = 32; off; off >>= 1) m = fmaxf(m, __shfl_xor(m, off));
        // phase 2: exp + sum
        float sum = 0.f;
#pragma unroll
        for (int c = 0; c < 4; ++c) {
            const int i = r0 + c * 64 + lane;
            const float ex = (i < r1) ? expf(s_reg[c] - m) : 0.f;
            s_reg[c] = ex;
            sum += ex;
        }
        for (int i = r0 + 256 + lane; i < r1; i += 64) sum += expf(score[csr[i]] - m);
#pragma unroll
        for (int off = 32; off; off >>= 1) sum += __shfl_xor(sum, off);
        const float inv = 1.f / sum;
        // phase 3: alpha scatter + shfl-broadcast aggregation
        float4 acc = make_float4(0.f, 0.f, 0.f, 0.f);
#pragma unroll
        for (int c = 0; c < 4; ++c) {
            const int base = r0 + c * 64;
            if (base < r1) {
                const int i = base + lane;
                float a = 0.f; int sn = 0;
                if (i < r1) {
                    a = s_reg[c] * inv;
                    sn = src[e_reg[c]];
                    att[(size_t)sn * MM + node] = a;
                }
                const int cnt = min(64, r1 - base);
                for (int j = 0; j < cnt; ++j) {
                    const float aj = __shfl(a, j);
                    const int sj = __shfl(sn, j);
                    const float4 hv = h4[(size_t)sj * 64 + lane];
                    acc.x += aj * hv.x; acc.y += aj * hv.y;
                    acc.z += aj * hv.z; acc.w += aj * hv.w;
                }
            }
        }
        for (int base = r0 + 256; base < r1; base += 64) {  // overflow (deg>256)
            const int i = base + lane;
            float a = 0.f; int sn = 0;
            if (i < r1) {
                const int e = csr[i];
                a = expf(score[e] - m) * inv;
                sn = src[e];
                att[(size_t)sn * MM + node] = a;
            }
            const int cnt = min(64, r1 - base);
            for (int j = 0; j < cnt; ++j) {
                const float aj = __shfl(a, j);
                const int sj = __shfl(sn, j);
                const float4 hv = h4[(size_t)sj * 64 + lane];
                acc.x += aj * hv.x; acc.y += aj * hv.y;
                acc.z += aj * hv.z; acc.w += aj * hv.w;
            }
        }
        out4[(size_t)node * 64 + lane] = acc;
    }
}

// ---------------------------------------------------------------------------
extern "C" void kernel_launch(void* const* d_in, const int* in_sizes, int n_in,
                              void* d_out, int out_size, void* d_ws, size_t ws_size,
                              hipStream_t stream) {
    const float* x       = (const float*)d_in[0];
    const float* W       = (const float*)d_in[1];
    const float* att_src = (const float*)d_in[2];
    const float* att_dst = (const float*)d_in[3];
    const int*   eidx    = (const int*)d_in[4];
    float* out = (float*)d_out;
    float* ws  = (float*)d_ws;

    // zero deg[MM] and the fill counter (adjacent) in one small memset
    hipMemsetAsync((char*)d_ws + O_DEG * 4, 0, (MM + 1) * sizeof(int), stream);

    void* kargs[] = {(void*)&x, (void*)&W, (void*)&att_src, (void*)&att_dst,
                     (void*)&eidx, (void*)&out, (void*)&ws};
    hipLaunchCooperativeKernel((void*)gat_fused, dim3(GRID), dim3(BLK),
                               kargs, 0, stream);
}

// Round 5
// 550.151 us; speedup vs baseline: 1.7270x; 1.7270x over previous
//
#include <hip/hip_runtime.h>
#include <math.h>

constexpr int MM = 10000;   // N_NODES
constexpr int DD = 256;     // D_IN == D_OUT
constexpr int EE = 320000;  // N_EDGES

// attention-matrix zero-fill partition (float4 units; total = MM*MM/4 = 25e6)
constexpr size_t ZT = (size_t)MM * MM / 4;   // 25,000,000
constexpr size_t Z1 = 11250000;              // gemm slice         (180 MB)
constexpr size_t Z2 = 16250000;              // dots slice          (80 MB)
                                             // scoreScatter: [Z2,ZT) (140 MB)

__device__ __forceinline__ void zero_att_slice(float4* att4, size_t lo, size_t hi) {
    const size_t stride = (size_t)gridDim.x * blockDim.x;
    for (size_t p = lo + (size_t)blockIdx.x * blockDim.x + threadIdx.x; p < hi; p += stride)
        att4[p] = make_float4(0.f, 0.f, 0.f, 0.f);
}

// ---------------------------------------------------------------------------
// GEMM: H = X @ W^T (fp32), 64x64 tile, BK=16, 256 thr, 4x4 micro-tile.
// Carries 180 MB of the attention-matrix zero-fill (stores drain under compute).
// ---------------------------------------------------------------------------
__global__ __launch_bounds__(256) void gemm_h(const float* __restrict__ X,
                                              const float* __restrict__ W,
                                              float* __restrict__ H,
                                              float4* __restrict__ att4) {
    zero_att_slice(att4, 0, Z1);

    __shared__ float xs[16][68];
    __shared__ float ws[16][68];
    const int tid = threadIdx.x;
    const int bid = blockIdx.x;
    const int bm = (bid % 157) << 6;
    const int bn = (bid / 157) << 6;
    const int lr = tid >> 2;          // 0..63
    const int lc = (tid & 3) << 2;    // 0,4,8,12
    const int tx = tid & 15;
    const int ty = tid >> 4;

    float acc[4][4] = {};

    for (int k0 = 0; k0 < DD; k0 += 16) {
        const int gr = bm + lr;
        float4 xv = make_float4(0.f, 0.f, 0.f, 0.f);
        if (gr < MM) xv = *(const float4*)(X + (size_t)gr * DD + k0 + lc);
        float4 wv = *(const float4*)(W + (size_t)(bn + lr) * DD + k0 + lc);
        xs[lc + 0][lr] = xv.x; xs[lc + 1][lr] = xv.y;
        xs[lc + 2][lr] = xv.z; xs[lc + 3][lr] = xv.w;
        ws[lc + 0][lr] = wv.x; ws[lc + 1][lr] = wv.y;
        ws[lc + 2][lr] = wv.z; ws[lc + 3][lr] = wv.w;
        __syncthreads();
#pragma unroll
        for (int k = 0; k < 16; ++k) {
            float4 xr4 = *(const float4*)(&xs[k][ty << 2]);
            float4 wr4 = *(const float4*)(&ws[k][tx << 2]);
            float xr[4] = {xr4.x, xr4.y, xr4.z, xr4.w};
            float wr[4] = {wr4.x, wr4.y, wr4.z, wr4.w};
#pragma unroll
            for (int i = 0; i < 4; ++i)
#pragma unroll
                for (int j = 0; j < 4; ++j) acc[i][j] += xr[i] * wr[j];
        }
        __syncthreads();
    }
#pragma unroll
    for (int i = 0; i < 4; ++i) {
        const int r = bm + (ty << 2) + i;
        if (r < MM) {
            *(float4*)(H + (size_t)r * DD + bn + (tx << 2)) =
                make_float4(acc[i][0], acc[i][1], acc[i][2], acc[i][3]);
        }
    }
}

// ---------------------------------------------------------------------------
// Per-node dots (wave per node) + degree counting + 80 MB fill slice.
// ---------------------------------------------------------------------------
__global__ __launch_bounds__(256) void node_dots_deg(const float* __restrict__ h,
                                                     const float* __restrict__ att_src,
                                                     const float* __restrict__ att_dst,
                                                     const int* __restrict__ dst,
                                                     float* __restrict__ s_src,
                                                     float* __restrict__ s_dst,
                                                     int* __restrict__ deg,
                                                     float4* __restrict__ att4) {
    zero_att_slice(att4, Z1, Z2);

    const int wv = threadIdx.x >> 6, lane = threadIdx.x & 63;
    const int node = blockIdx.x * 4 + wv;
    if (node < MM) {
        float4 a = ((const float4*)att_src)[lane];
        float4 b = ((const float4*)att_dst)[lane];
        float4 v = ((const float4*)h)[(size_t)node * 64 + lane];
        float ds = v.x * a.x + v.y * a.y + v.z * a.z + v.w * a.w;
        float dd = v.x * b.x + v.y * b.y + v.z * b.z + v.w * b.w;
#pragma unroll
        for (int off = 32; off; off >>= 1) {
            ds += __shfl_xor(ds, off);
            dd += __shfl_xor(dd, off);
        }
        if (lane == 0) { s_src[node] = ds; s_dst[node] = dd; }
    }
    // degree counting (edge-indexed grid-stride; independent of dots)
    const int gt = blockIdx.x * 256 + threadIdx.x;
    for (int e = gt; e < EE; e += gridDim.x * 256) atomicAdd(&deg[dst[e]], 1);
}

// ---------------------------------------------------------------------------
// Exclusive scan of deg -> row_off[MM+1], cursor. 1 block, 1024 thr, 2 barriers.
// ---------------------------------------------------------------------------
__global__ __launch_bounds__(1024) void scan_deg(const int* __restrict__ deg,
                                                 int* __restrict__ row_off,
                                                 int* __restrict__ cursor) {
    constexpr int C = 10;  // 1024*10 >= MM
    __shared__ int wsum[16];
    const int t = threadIdx.x, wv = t >> 6, lane = t & 63;
    const int i0 = t * C;
    int total = 0;
#pragma unroll
    for (int k = 0; k < C; ++k) {
        const int i = i0 + k;
        total += (i < MM) ? deg[i] : 0;
    }
    int incl = total;
#pragma unroll
    for (int off = 1; off < 64; off <<= 1) {
        int u = __shfl_up(incl, off);
        if (lane >= off) incl += u;
    }
    if (lane == 63) wsum[wv] = incl;
    __syncthreads();
    if (t < 16) {
        int v = wsum[t];
#pragma unroll
        for (int off = 1; off < 16; off <<= 1) {
            int u = __shfl_up(v, off);
            if (t >= off) v += u;
        }
        wsum[t] = v;
    }
    __syncthreads();
    const int wave_excl = (wv == 0) ? 0 : wsum[wv - 1];
    int run = wave_excl + incl - total;  // global exclusive prefix
#pragma unroll
    for (int k = 0; k < C; ++k) {
        const int i = i0 + k;
        if (i < MM) {
            const int v = deg[i];
            cursor[i] = run;
            run += v;
            row_off[i + 1] = run;
        }
    }
    if (t == 0) row_off[0] = 0;
}

// ---------------------------------------------------------------------------
// Fused per-edge: score + CSR scatter + 140 MB fill slice. 1250*256 == EE.
// ---------------------------------------------------------------------------
__global__ __launch_bounds__(256) void score_scatter(const int* __restrict__ src,
                                                     const int* __restrict__ dst,
                                                     const float* __restrict__ s_src,
                                                     const float* __restrict__ s_dst,
                                                     float* __restrict__ score,
                                                     int* __restrict__ cursor,
                                                     int* __restrict__ csr,
                                                     float4* __restrict__ att4) {
    zero_att_slice(att4, Z2, ZT);
    const int e = blockIdx.x * 256 + threadIdx.x;
    const int s = src[e], d = dst[e];
    float sc = s_src[s] + s_dst[d];
    sc = (sc >= 0.f) ? sc : 0.2f * sc;
    score[e] = sc;
    const int pos = atomicAdd(&cursor[d], 1);
    csr[pos] = e;
}

// ---------------------------------------------------------------------------
// Wave-per-node softmax + attention scatter + aggregation (barrier/LDS-free).
// ---------------------------------------------------------------------------
__global__ __launch_bounds__(256) void node_agg(const float* __restrict__ h,
                                                const float* __restrict__ score,
                                                const int* __restrict__ src,
                                                const int* __restrict__ csr,
                                                const int* __restrict__ row_off,
                                                float* __restrict__ out,
                                                float* __restrict__ att) {
    const int wv = threadIdx.x >> 6, lane = threadIdx.x & 63;
    const int node = blockIdx.x * 4 + wv;
    if (node >= MM) return;
    const int r0 = row_off[node], r1 = row_off[node + 1];
    const float4* h4 = (const float4*)h;
    float4* out4 = (float4*)out;

    if (r0 == r1) {  // no incoming edges: keep own transformed features
        out4[(size_t)node * 64 + lane] = h4[(size_t)node * 64 + lane];
        return;
    }

    // phase 1: max (cache first 4 chunks in registers)
    int e_reg[4];
    float s_reg[4];
    float m = -INFINITY;
#pragma unroll
    for (int c = 0; c < 4; ++c) {
        const int i = r0 + c * 64 + lane;
        const bool vld = i < r1;
        const int e = vld ? csr[i] : 0;
        const float s = vld ? score[e] : -INFINITY;
        e_reg[c] = e; s_reg[c] = s;
        m = fmaxf(m, s);
    }
    for (int i = r0 + 256 + lane; i < r1; i += 64) m = fmaxf(m, score[csr[i]]);
#pragma unroll
    for (int off = 32; off; off >>= 1) m = fmaxf(m, __shfl_xor(m, off));

    // phase 2: exp + sum (s_reg becomes ex)
    float sum = 0.f;
#pragma unroll
    for (int c = 0; c < 4; ++c) {
        const int i = r0 + c * 64 + lane;
        const float ex = (i < r1) ? expf(s_reg[c] - m) : 0.f;
        s_reg[c] = ex;
        sum += ex;
    }
    for (int i = r0 + 256 + lane; i < r1; i += 64) sum += expf(score[csr[i]] - m);
#pragma unroll
    for (int off = 32; off; off >>= 1) sum += __shfl_xor(sum, off);
    const float inv = 1.f / sum;

    // phase 3: alpha scatter + shfl-broadcast aggregation (float4 channels)
    float4 acc = make_float4(0.f, 0.f, 0.f, 0.f);
#pragma unroll
    for (int c = 0; c < 4; ++c) {
        const int base = r0 + c * 64;
        if (base < r1) {
            const int i = base + lane;
            float a = 0.f; int sn = 0;
            if (i < r1) {
                a = s_reg[c] * inv;
                sn = src[e_reg[c]];
                att[(size_t)sn * MM + node] = a;
            }
            const int cnt = min(64, r1 - base);
            for (int j = 0; j < cnt; ++j) {
                const float aj = __shfl(a, j);
                const int sj = __shfl(sn, j);
                const float4 hv = h4[(size_t)sj * 64 + lane];
                acc.x += aj * hv.x; acc.y += aj * hv.y;
                acc.z += aj * hv.z; acc.w += aj * hv.w;
            }
        }
    }
    for (int base = r0 + 256; base < r1; base += 64) {  // overflow (deg>256)
        const int i = base + lane;
        float a = 0.f; int sn = 0;
        if (i < r1) {
            const int e = csr[i];
            a = expf(score[e] - m) * inv;
            sn = src[e];
            att[(size_t)sn * MM + node] = a;
        }
        const int cnt = min(64, r1 - base);
        for (int j = 0; j < cnt; ++j) {
            const float aj = __shfl(a, j);
            const int sj = __shfl(sn, j);
            const float4 hv = h4[(size_t)sj * 64 + lane];
            acc.x += aj * hv.x; acc.y += aj * hv.y;
            acc.z += aj * hv.z; acc.w += aj * hv.w;
        }
    }
    out4[(size_t)node * 64 + lane] = acc;
}

// ---------------------------------------------------------------------------
extern "C" void kernel_launch(void* const* d_in, const int* in_sizes, int n_in,
                              void* d_out, int out_size, void* d_ws, size_t ws_size,
                              hipStream_t stream) {
    const float* x       = (const float*)d_in[0];
    const float* W       = (const float*)d_in[1];
    const float* att_src = (const float*)d_in[2];
    const float* att_dst = (const float*)d_in[3];
    const int*   eidx    = (const int*)d_in[4];
    const int* src = eidx;
    const int* dst = eidx + EE;

    float* out_feat = (float*)d_out;               // [10000,256]
    float* att      = out_feat + (size_t)MM * DD;  // [10000,10000]
    float4* att4    = (float4*)att;

    float* h       = (float*)d_ws;                  // MM*DD
    float* s_src   = h + (size_t)MM * DD;           // MM
    float* s_dst   = s_src + MM;                    // MM
    float* score   = s_dst + MM;                    // EE
    int*   deg     = (int*)(score + EE);            // MM
    int*   row_off = deg + MM;                      // MM+1
    int*   cursor  = row_off + MM + 1;              // MM
    int*   csr     = cursor + MM;                   // EE

    hipMemsetAsync(deg, 0, MM * sizeof(int), stream);

    gemm_h<<<628, 256, 0, stream>>>(x, W, h, att4);
    node_dots_deg<<<2500, 256, 0, stream>>>(h, att_src, att_dst, dst,
                                            s_src, s_dst, deg, att4);
    scan_deg<<<1, 1024, 0, stream>>>(deg, row_off, cursor);
    score_scatter<<<1250, 256, 0, stream>>>(src, dst, s_src, s_dst,
                                            score, cursor, csr, att4);
    node_agg<<<2500, 256, 0, stream>>>(h, score, src, csr, row_off, out_feat, att);
}